// Round 6
// baseline (144.707 us; speedup 1.0000x reference)
//
#include <hip/hip_runtime.h>

namespace {

constexpr int kB  = 16;    // batches
constexpr int kP  = 8;     // pieces
constexpr int kNT = 512;   // time steps (incl. t=0)
constexpr int kNX = 2048;  // cells
constexpr int kW  = 64;    // steps per super-step
constexpr int kChunk = 128;               // cells owned per wave
constexpr int kNS = 8;                    // super-steps: 7*64 + 63 = 511 rows
// region per wave = kChunk + 2*kW = 256 cells = 64 lanes x 4 cells

// d_ws layout
constexpr size_t kFlagsOff = 0;                      // int flags[B][16][kNS]
constexpr size_t kFlagsBytes = (size_t)kB * 16 * kNS * 4;   // 8 KB
constexpr size_t kHaloOff  = 32768;                  // float halo[B][16][kNS][kChunk]

// Cross-lane shift by one lane via DPP (VALU; no LDS round-trip).
__device__ __forceinline__ float dpp_shr1(float x) {
    return __builtin_bit_cast(float,
        __builtin_amdgcn_update_dpp(0, __builtin_bit_cast(int, x), 0x138, 0xF, 0xF, true));
}
__device__ __forceinline__ float dpp_shl1(float x) {
    return __builtin_bit_cast(float,
        __builtin_amdgcn_update_dpp(0, __builtin_bit_cast(int, x), 0x130, 0xF, 0xF, true));
}

__device__ __forceinline__ float fpar(float u) {  // f(u) = u - u^2
    return __builtin_fmaf(-u, u, u);
}

__global__ __launch_bounds__(64)
void godunov_fused(const float* __restrict__ xs,   // (B, P+1)
                   const float* __restrict__ ks,   // (B, P)
                   const int*   __restrict__ pm,   // (B, P)
                   const float* __restrict__ dxp,  // (B,)
                   const float* __restrict__ dtp,  // (B,)
                   float* __restrict__ out,        // (B,1,NT,NX) fp32
                   int*   __restrict__ flags,      // [B][16][kNS], pre-zeroed
                   float* __restrict__ halo)       // [B][16][kNS][kChunk]
{
    const int bx   = blockIdx.x;
    const int b    = bx >> 4;        // batch
    const int k    = bx & 15;        // chunk within batch
    const int lane = threadIdx.x;    // 0..63, one wave per block
    const int rs   = k * kChunk - kW;    // region start (may be <0)
    const int gi0  = rs + 4 * lane;      // this lane's first cell

    const float dxv = dxp[0];
    const float lam = dtp[0] / dxv;

    // ---- piecewise-constant IC parameters ----
    int np = 0;
    float bnds[kP];
#pragma unroll
    for (int j = 0; j < kP; ++j) {
        int m = pm[b * kP + j];
        np += m;
        bnds[j] = m ? xs[b * (kP + 1) + j + 1] : __builtin_inff();
    }
    const int cap = np - 1;

    auto icval = [&](int gi) -> float {
        float xc = ((float)gi + 0.5f) * dxv;
        int idx = 0;
#pragma unroll
        for (int j = 0; j < kP; ++j) idx += (xc >= bnds[j]) ? 1 : 0;
        idx = min(idx, cap);
        return ks[b * kP + idx];
    };

    // Constant ghost values (reference: frozen IC endpoints).
    const float gL = icval(0);
    const float gR = icval(kNX - 1);

    // Per-cell domain mask + ghost value (cells outside [0,NX) pinned).
    bool  inD[4];
    float gv[4];
#pragma unroll
    for (int c = 0; c < 4; ++c) {
        int gi = gi0 + c;
        inD[c] = (gi >= 0) && (gi < kNX);
        gv[c]  = (gi < 0) ? gL : gR;
    }

    // ---- seed at t=0 from IC ----
    float u[4];
#pragma unroll
    for (int c = 0; c < 4; ++c)
        u[c] = inD[c] ? icval(gi0 + c) : gv[c];

    // Lanes 16..47 own exactly the chunk (cells k*128 .. k*128+127).
    const bool writer = (lane >= 16) && (lane < 48);
    float* prow = out + ((size_t)b * kNT) * kNX;  // row 0

    if (writer)
        *reinterpret_cast<float4*>(prow + gi0) = make_float4(u[0], u[1], u[2], u[3]);

    const int fbase = (b * 16 + k) * kNS;  // own flag/halo base index

#pragma unroll 1
    for (int s = 0; s < kNS; ++s) {
        // ---- re-seed halo lanes from neighbors (state at time 64*s) ----
        if (s > 0) {
            const bool needL = (k > 0), needR = (k < 15);
            const int* fL = flags + ((b * 16 + (k - 1)) * kNS + s);
            const int* fR = flags + ((b * 16 + (k + 1)) * kNS + s);
            // uniform spin (all lanes same addresses); acquire gives ordering
            for (int it = 0; it < (1 << 22); ++it) {
                int okL = needL ? __hip_atomic_load(fL, __ATOMIC_ACQUIRE,
                                                    __HIP_MEMORY_SCOPE_AGENT) : 1;
                int okR = needR ? __hip_atomic_load(fR, __ATOMIC_ACQUIRE,
                                                    __HIP_MEMORY_SCOPE_AGENT) : 1;
                if (okL && okR) break;
                __builtin_amdgcn_s_sleep(2);
            }
            if (lane < 16) {
                if (needL) {  // left neighbor's cells 64..127
                    const float* hp = halo + ((size_t)((b * 16 + (k - 1)) * kNS + s)) * kChunk
                                    + 64 + 4 * lane;
#pragma unroll
                    for (int c = 0; c < 4; ++c)
                        u[c] = __hip_atomic_load(hp + c, __ATOMIC_RELAXED,
                                                 __HIP_MEMORY_SCOPE_AGENT);
                }  // k==0: lanes stay pinned at gL
            } else if (lane >= 48) {
                if (needR) {  // right neighbor's cells 0..63
                    const float* hp = halo + ((size_t)((b * 16 + (k + 1)) * kNS + s)) * kChunk
                                    + 4 * (lane - 48);
#pragma unroll
                    for (int c = 0; c < 4; ++c)
                        u[c] = __hip_atomic_load(hp + c, __ATOMIC_RELAXED,
                                                 __HIP_MEMORY_SCOPE_AGENT);
                }  // k==15: lanes stay pinned at gR
            }
            // lanes 16..47 keep their registers (own chunk, still valid)
        }

        const int nsteps = (s == kNS - 1) ? (kW - 1) : kW;  // 7*64 + 63 = 511

#pragma unroll 1
        for (int j = 0; j < nsteps; ++j) {
            // halo exchange via DPP (no LDS, no barrier)
            float um = dpp_shr1(u[3]);    // cell gi0-1
            float up = dpp_shl1(u[0]);    // cell gi0+4

            // Godunov flux, branchless concave form:
            //   F(uL,uR) = min( f(min(uL,1/2)), f(max(uR,1/2)) )
            float fl[4], fh[4];
#pragma unroll
            for (int c = 0; c < 4; ++c) {
                fl[c] = fpar(fminf(u[c], 0.5f));
                fh[c] = fpar(fmaxf(u[c], 0.5f));
            }
            float flm = fpar(fminf(um, 0.5f));
            float fhp = fpar(fmaxf(up, 0.5f));

            float F[5];
            F[0] = fminf(flm,   fh[0]);
            F[1] = fminf(fl[0], fh[1]);
            F[2] = fminf(fl[1], fh[2]);
            F[3] = fminf(fl[2], fh[3]);
            F[4] = fminf(fl[3], fhp);

#pragma unroll
            for (int c = 0; c < 4; ++c) {
                float un = __builtin_fmaf(-lam, F[c + 1] - F[c], u[c]);
                u[c] = inD[c] ? un : gv[c];   // pin out-of-domain cells
            }

            prow += kNX;
            if (writer)
                *reinterpret_cast<float4*>(prow + gi0) = make_float4(u[0], u[1], u[2], u[3]);
        }

        // ---- publish own chunk state (time 64*(s+1)) + release flag ----
        if (s < kNS - 1) {
            if (writer) {
                float* hp = halo + ((size_t)(fbase + (s + 1))) * kChunk + 4 * (lane - 16);
#pragma unroll
                for (int c = 0; c < 4; ++c)
                    __hip_atomic_store(hp + c, u[c], __ATOMIC_RELAXED,
                                       __HIP_MEMORY_SCOPE_AGENT);
            }
            if (lane == 0)
                __hip_atomic_store(flags + fbase + (s + 1), 1, __ATOMIC_RELEASE,
                                   __HIP_MEMORY_SCOPE_AGENT);
        }
    }
}

}  // namespace

extern "C" void kernel_launch(void* const* d_in, const int* in_sizes, int n_in,
                              void* d_out, int out_size, void* d_ws, size_t ws_size,
                              hipStream_t stream) {
    const float* xs  = (const float*)d_in[0];
    const float* ks  = (const float*)d_in[1];
    const int*   pm  = (const int*)d_in[2];
    const float* dxv = (const float*)d_in[3];
    const float* dtv = (const float*)d_in[4];
    // d_in[5] = t_coords: only carries the (NT, NX) shape; values unused.
    float* out = (float*)d_out;

    int*   flags = (int*)((char*)d_ws + kFlagsOff);
    float* halo  = (float*)((char*)d_ws + kHaloOff);

    // Flags must be zeroed every call (d_ws is not re-poisoned between replays).
    hipMemsetAsync(flags, 0, kFlagsBytes, stream);

    hipLaunchKernelGGL(godunov_fused, dim3(kB * 16), dim3(64), 0, stream,
                       xs, ks, pm, dxv, dtv, out, flags, halo);
}

// Round 7
// 97.395 us; speedup vs baseline: 1.4858x; 1.4858x over previous
//
#include <hip/hip_runtime.h>

namespace {

constexpr int kB  = 16;    // batches
constexpr int kP  = 8;     // pieces
constexpr int kNT = 512;   // time steps (incl. t=0)
constexpr int kNX = 2048;  // cells
constexpr int kW  = 64;    // time steps advanced per launch (constant)
constexpr int kChunk = 128;                 // cells owned per wave
constexpr int kChunksPerB = kNX / kChunk;   // 16
// region per wave = kChunk + 2*kW = 256 cells = 64 lanes x 4 cells

// Cross-lane shift by one lane via DPP (VALU; no LDS round-trip).
__device__ __forceinline__ float dpp_shr1(float x) {
    return __builtin_bit_cast(float,
        __builtin_amdgcn_update_dpp(0, __builtin_bit_cast(int, x), 0x138, 0xF, 0xF, true));
}
__device__ __forceinline__ float dpp_shl1(float x) {
    return __builtin_bit_cast(float,
        __builtin_amdgcn_update_dpp(0, __builtin_bit_cast(int, x), 0x130, 0xF, 0xF, true));
}

__device__ __forceinline__ float fpar(float u) {  // f(u) = u - u^2
    return __builtin_fmaf(-u, u, u);
}

__global__ __launch_bounds__(64)
void godunov_step(const float* __restrict__ xs,   // (B, P+1)
                  const float* __restrict__ ks,   // (B, P)
                  const int*   __restrict__ pm,   // (B, P)
                  const float* __restrict__ dxp,  // (B,)
                  const float* __restrict__ dtp,  // (B,)
                  float* __restrict__ out,        // (B,1,NT,NX) fp32
                  int t0, int skipLast)           // rows t0+1..t0+64 (last store skipped if skipLast)
{
    const int bx   = blockIdx.x;
    const int b    = bx >> 4;        // batch
    const int k    = bx & 15;        // chunk within batch
    const int lane = threadIdx.x;    // 0..63, one wave per block
    const int rs   = k * kChunk - kW;    // region start (may be <0)
    const int gi0  = rs + 4 * lane;      // this lane's first cell

    const float dxv = dxp[0];
    const float lam = dtp[0] / dxv;

    // ---- piecewise-constant IC parameters ----
    int np = 0;
    float bnds[kP];
#pragma unroll
    for (int j = 0; j < kP; ++j) {
        int m = pm[b * kP + j];
        np += m;
        bnds[j] = m ? xs[b * (kP + 1) + j + 1] : __builtin_inff();
    }
    const int cap = np - 1;

    auto icval = [&](int gi) -> float {
        float xc = ((float)gi + 0.5f) * dxv;
        int idx = 0;
#pragma unroll
        for (int j = 0; j < kP; ++j) idx += (xc >= bnds[j]) ? 1 : 0;
        idx = min(idx, cap);
        return ks[b * kP + idx];
    };

    // Constant ghost values (reference: frozen IC endpoints).
    const float gL = icval(0);
    const float gR = icval(kNX - 1);

    // Region is 4-aligned and domain edges are multiples of 4, so each lane's
    // 4 cells are all-in or all-out of the domain: one mask per lane.
    const bool  laneIn  = (gi0 >= 0) && (gi0 < kNX);
    const float gvv     = (gi0 < 0) ? gL : gR;
    const bool  edgeBlk = (k == 0) || (k == kChunksPerB - 1);  // only these ever pin

    // ---- seed region state at row t0 ----
    float u[4];
    if (t0 == 0) {
#pragma unroll
        for (int c = 0; c < 4; ++c)
            u[c] = laneIn ? icval(gi0 + c) : gvv;
    } else {
        if (laneIn) {
            const float* rin = out + ((size_t)b * kNT + t0) * kNX;
            float4 v = *reinterpret_cast<const float4*>(rin + gi0);
            u[0] = v.x; u[1] = v.y; u[2] = v.z; u[3] = v.w;
        } else {
            u[0] = gvv; u[1] = gvv; u[2] = gvv; u[3] = gvv;
        }
    }

    // Lanes 16..47 own exactly the chunk (cells k*128 .. k*128+127).
    const bool writer = (lane >= 16) && (lane < 48);

    if (t0 == 0 && writer) {
        float* p0 = out + ((size_t)b * kNT) * kNX;
        *reinterpret_cast<float4*>(p0 + gi0) = make_float4(u[0], u[1], u[2], u[3]);
    }

    // One Godunov step: u <- u - lam*(F_r - F_l), branchless concave flux
    //   F(uL,uR) = min( f(min(uL,1/2)), f(max(uR,1/2)) )
    auto do_step = [&]() {
        float um = dpp_shr1(u[3]);    // cell gi0-1
        float up = dpp_shl1(u[0]);    // cell gi0+4
        float fl[4], fh[4];
#pragma unroll
        for (int c = 0; c < 4; ++c) {
            fl[c] = fpar(fminf(u[c], 0.5f));
            fh[c] = fpar(fmaxf(u[c], 0.5f));
        }
        float flm = fpar(fminf(um, 0.5f));
        float fhp = fpar(fmaxf(up, 0.5f));
        float F0 = fminf(flm,   fh[0]);
        float F1 = fminf(fl[0], fh[1]);
        float F2 = fminf(fl[1], fh[2]);
        float F3 = fminf(fl[2], fh[3]);
        float F4 = fminf(fl[3], fhp);
        u[0] = __builtin_fmaf(-lam, F1 - F0, u[0]);
        u[1] = __builtin_fmaf(-lam, F2 - F1, u[1]);
        u[2] = __builtin_fmaf(-lam, F3 - F2, u[2]);
        u[3] = __builtin_fmaf(-lam, F4 - F3, u[3]);
        if (edgeBlk) {   // wave-uniform; skipped by 14/16 blocks
#pragma unroll
            for (int c = 0; c < 4; ++c) u[c] = laneIn ? u[c] : gvv;
        }
    };

    float* pcur = out + ((size_t)b * kNT + t0 + 1) * kNX;  // row t0+1

    // 4 groups x 16 steps. st[16] + fake-use keeps 16 store-data register sets
    // live to the group end -> register reuse happens >=16 stores later -> the
    // compiler's WAR s_waitcnt vmcnt(N) is satisfied without stalling
    // (store-ack latency ~300cyc << 16 steps of work).
#pragma unroll 1
    for (int g = 0; g < kW / 16; ++g) {
        float4 st[16];
        const bool skipTail = skipLast && (g == kW / 16 - 1);
#pragma unroll
        for (int q = 0; q < 16; ++q) {
            do_step();
            st[q] = make_float4(u[0], u[1], u[2], u[3]);
            bool doStore = writer;
            if (q == 15 && skipTail) doStore = false;  // row t0+64 may not exist
            if (doStore)
                *reinterpret_cast<float4*>(pcur + gi0) = st[q];
            pcur += kNX;
        }
        asm volatile("" :: "v"(st[0].x), "v"(st[0].y), "v"(st[0].z), "v"(st[0].w),
                           "v"(st[1].x), "v"(st[1].y), "v"(st[1].z), "v"(st[1].w),
                           "v"(st[2].x), "v"(st[2].y), "v"(st[2].z), "v"(st[2].w),
                           "v"(st[3].x), "v"(st[3].y), "v"(st[3].z), "v"(st[3].w));
        asm volatile("" :: "v"(st[4].x), "v"(st[4].y), "v"(st[4].z), "v"(st[4].w),
                           "v"(st[5].x), "v"(st[5].y), "v"(st[5].z), "v"(st[5].w),
                           "v"(st[6].x), "v"(st[6].y), "v"(st[6].z), "v"(st[6].w),
                           "v"(st[7].x), "v"(st[7].y), "v"(st[7].z), "v"(st[7].w));
        asm volatile("" :: "v"(st[8].x), "v"(st[8].y), "v"(st[8].z), "v"(st[8].w),
                           "v"(st[9].x), "v"(st[9].y), "v"(st[9].z), "v"(st[9].w),
                           "v"(st[10].x), "v"(st[10].y), "v"(st[10].z), "v"(st[10].w),
                           "v"(st[11].x), "v"(st[11].y), "v"(st[11].z), "v"(st[11].w));
        asm volatile("" :: "v"(st[12].x), "v"(st[12].y), "v"(st[12].z), "v"(st[12].w),
                           "v"(st[13].x), "v"(st[13].y), "v"(st[13].z), "v"(st[13].w),
                           "v"(st[14].x), "v"(st[14].y), "v"(st[14].z), "v"(st[14].w),
                           "v"(st[15].x), "v"(st[15].y), "v"(st[15].z), "v"(st[15].w));
    }
}

}  // namespace

extern "C" void kernel_launch(void* const* d_in, const int* in_sizes, int n_in,
                              void* d_out, int out_size, void* d_ws, size_t ws_size,
                              hipStream_t stream) {
    const float* xs  = (const float*)d_in[0];
    const float* ks  = (const float*)d_in[1];
    const int*   pm  = (const int*)d_in[2];
    const float* dxv = (const float*)d_in[3];
    const float* dtv = (const float*)d_in[4];
    // d_in[5] = t_coords: only carries the (NT, NX) shape; values unused.
    float* out = (float*)d_out;

    // Ghost-zone temporal blocking: each launch advances kW=64 rows; halos are
    // re-seeded from the previous launch's output rows (stream-ordered, cache
    // coherence guaranteed at kernel boundaries). Last launch computes a 65th
    // step but skips its (nonexistent) row-512 store.
    for (int t0 = 0; t0 < kNT - 1; t0 += kW) {
        int skipLast = (t0 + kW > kNT - 1) ? 1 : 0;
        hipLaunchKernelGGL(godunov_step, dim3(kB * kChunksPerB), dim3(64), 0, stream,
                           xs, ks, pm, dxv, dtv, out, t0, skipLast);
    }
}

// Round 8
// 94.451 us; speedup vs baseline: 1.5321x; 1.0312x over previous
//
#include <hip/hip_runtime.h>

namespace {

constexpr int kB  = 16;    // batches
constexpr int kP  = 8;     // pieces
constexpr int kNT = 512;   // time steps (incl. t=0)
constexpr int kNX = 2048;  // cells
constexpr int kW  = 64;    // steps per super-step
constexpr int kChunk = 128;               // cells owned per wave
constexpr int kNS = 8;                    // super-steps: 7*64 + 63 = 511 rows
// region per wave = kChunk + 2*kW = 256 cells = 64 lanes x 4 cells

// d_ws layout
constexpr size_t kFlagsOff   = 0;                          // int flags[B][16][kNS]
constexpr size_t kFlagsBytes = (size_t)kB * 16 * kNS * 4;  // 8 KB
constexpr size_t kHaloOff    = 32768;                      // int halo[B][16][kNS][kChunk]

// Cross-lane shift by one lane via DPP (VALU; no LDS round-trip).
__device__ __forceinline__ float dpp_shr1(float x) {
    return __builtin_bit_cast(float,
        __builtin_amdgcn_update_dpp(0, __builtin_bit_cast(int, x), 0x138, 0xF, 0xF, true));
}
__device__ __forceinline__ float dpp_shl1(float x) {
    return __builtin_bit_cast(float,
        __builtin_amdgcn_update_dpp(0, __builtin_bit_cast(int, x), 0x130, 0xF, 0xF, true));
}

__device__ __forceinline__ float fpar(float u) {  // f(u) = u - u^2
    return __builtin_fmaf(-u, u, u);
}

// Relaxed agent-scope RMWs: execute at the coherence point (MALL), emit NO
// L2 writeback/invalidate (those come only from acquire/release semantics —
// the thing that killed the previous fused attempt).
__device__ __forceinline__ void mall_store(int* p, float v) {
    (void)__hip_atomic_exchange(p, __builtin_bit_cast(int, v),
                                __ATOMIC_RELAXED, __HIP_MEMORY_SCOPE_AGENT);
}
__device__ __forceinline__ float mall_load(int* p) {
    return __builtin_bit_cast(float,
        __hip_atomic_fetch_add(p, 0, __ATOMIC_RELAXED, __HIP_MEMORY_SCOPE_AGENT));
}

__global__ __launch_bounds__(64)
void godunov_fused(const float* __restrict__ xs,   // (B, P+1)
                   const float* __restrict__ ks,   // (B, P)
                   const int*   __restrict__ pm,   // (B, P)
                   const float* __restrict__ dxp,  // (B,)
                   const float* __restrict__ dtp,  // (B,)
                   float* __restrict__ out,        // (B,1,NT,NX) fp32
                   int*   __restrict__ flags,      // [B][16][kNS], pre-zeroed
                   int*   __restrict__ halo)       // [B][16][kNS][kChunk] (f32 bits)
{
    const int bx   = blockIdx.x;
    const int b    = bx >> 4;        // batch
    const int k    = bx & 15;        // chunk within batch
    const int lane = threadIdx.x;    // 0..63, one wave per block
    const int rs   = k * kChunk - kW;    // region start (may be <0)
    const int gi0  = rs + 4 * lane;      // this lane's first cell

    const float dxv = dxp[0];
    const float lam = dtp[0] / dxv;

    // ---- piecewise-constant IC parameters ----
    int np = 0;
    float bnds[kP];
#pragma unroll
    for (int j = 0; j < kP; ++j) {
        int m = pm[b * kP + j];
        np += m;
        bnds[j] = m ? xs[b * (kP + 1) + j + 1] : __builtin_inff();
    }
    const int cap = np - 1;

    auto icval = [&](int gi) -> float {
        float xc = ((float)gi + 0.5f) * dxv;
        int idx = 0;
#pragma unroll
        for (int j = 0; j < kP; ++j) idx += (xc >= bnds[j]) ? 1 : 0;
        idx = min(idx, cap);
        return ks[b * kP + idx];
    };

    // Constant ghost values (reference: frozen IC endpoints).
    const float gL = icval(0);
    const float gR = icval(kNX - 1);

    // Region is 4-aligned; each lane's 4 cells are all-in or all-out of domain.
    const bool  laneIn  = (gi0 >= 0) && (gi0 < kNX);
    const float gvv     = (gi0 < 0) ? gL : gR;
    const bool  edgeBlk = (k == 0) || (k == 15);   // only these ever pin

    // ---- seed at t=0 from IC ----
    float u[4];
#pragma unroll
    for (int c = 0; c < 4; ++c)
        u[c] = laneIn ? icval(gi0 + c) : gvv;

    // Lanes 16..47 own exactly the chunk (cells k*128 .. k*128+127).
    const bool writer = (lane >= 16) && (lane < 48);
    float* prow = out + ((size_t)b * kNT) * kNX;  // row 0

    if (writer)
        *reinterpret_cast<float4*>(prow + gi0) = make_float4(u[0], u[1], u[2], u[3]);

    const int fbase = (b * 16 + k) * kNS;

    auto do_step = [&]() {
        float um = dpp_shr1(u[3]);    // cell gi0-1
        float up = dpp_shl1(u[0]);    // cell gi0+4
        // Godunov flux, branchless concave form:
        //   F(uL,uR) = min( f(min(uL,1/2)), f(max(uR,1/2)) )
        float fl[4], fh[4];
#pragma unroll
        for (int c = 0; c < 4; ++c) {
            fl[c] = fpar(fminf(u[c], 0.5f));
            fh[c] = fpar(fmaxf(u[c], 0.5f));
        }
        float flm = fpar(fminf(um, 0.5f));
        float fhp = fpar(fmaxf(up, 0.5f));
        float F0 = fminf(flm,   fh[0]);
        float F1 = fminf(fl[0], fh[1]);
        float F2 = fminf(fl[1], fh[2]);
        float F3 = fminf(fl[2], fh[3]);
        float F4 = fminf(fl[3], fhp);
        u[0] = __builtin_fmaf(-lam, F1 - F0, u[0]);
        u[1] = __builtin_fmaf(-lam, F2 - F1, u[1]);
        u[2] = __builtin_fmaf(-lam, F3 - F2, u[2]);
        u[3] = __builtin_fmaf(-lam, F4 - F3, u[3]);
        if (edgeBlk) {   // wave-uniform; skipped by 14/16 blocks
#pragma unroll
            for (int c = 0; c < 4; ++c) u[c] = laneIn ? u[c] : gvv;
        }
    };

#pragma unroll 1
    for (int s = 0; s < kNS; ++s) {
        // ---- re-seed halo lanes from neighbors (state at time 64*s) ----
        if (s > 0) {
            const bool needL = (k > 0), needR = (k < 15);
            // lane-0-only spin: whole wave waits on the divergent branch;
            // 1 RMW per flag per poll (not 64 serialized same-address RMWs).
            if (lane == 0) {
                int* fL = flags + ((b * 16 + (k - 1)) * kNS + s);
                int* fR = flags + ((b * 16 + (k + 1)) * kNS + s);
                int okL = needL ? 0 : 1, okR = needR ? 0 : 1;
                for (int it = 0; it < (1 << 22); ++it) {
                    if (!okL) okL = __hip_atomic_fetch_add(fL, 0, __ATOMIC_RELAXED,
                                                           __HIP_MEMORY_SCOPE_AGENT);
                    if (!okR) okR = __hip_atomic_fetch_add(fR, 0, __ATOMIC_RELAXED,
                                                           __HIP_MEMORY_SCOPE_AGENT);
                    if (okL && okR) break;
                    __builtin_amdgcn_s_sleep(4);
                }
            }
            asm volatile("" ::: "memory");   // keep data reads below the spin

            if (lane < 16) {
                if (needL) {  // left neighbor's cells 64..127
                    int* hp = halo + ((size_t)((b * 16 + (k - 1)) * kNS + s)) * kChunk
                            + 64 + 4 * lane;
#pragma unroll
                    for (int c = 0; c < 4; ++c) u[c] = mall_load(hp + c);
                }  // k==0: lanes stay pinned at gL
            } else if (lane >= 48) {
                if (needR) {  // right neighbor's cells 0..63
                    int* hp = halo + ((size_t)((b * 16 + (k + 1)) * kNS + s)) * kChunk
                            + 4 * (lane - 48);
#pragma unroll
                    for (int c = 0; c < 4; ++c) u[c] = mall_load(hp + c);
                }  // k==15: lanes stay pinned at gR
            }
            // lanes 16..47 keep their registers (own chunk, still valid)
        }

        const int nsteps = (s == kNS - 1) ? (kW - 1) : kW;  // 7*64 + 63 = 511

#pragma unroll 1
        for (int j = 0; j < nsteps; ++j) {
            do_step();
            prow += kNX;
            if (writer)
                *reinterpret_cast<float4*>(prow + gi0) = make_float4(u[0], u[1], u[2], u[3]);
        }

        // ---- publish own chunk state (time 64*(s+1)) + flag, all relaxed ----
        if (s < kNS - 1) {
            if (writer) {
                int* hp = halo + ((size_t)(fbase + (s + 1))) * kChunk + 4 * (lane - 16);
#pragma unroll
                for (int c = 0; c < 4; ++c) mall_store(hp + c, u[c]);
            }
            // drain data RMWs (vmcnt covers global atomics), then set flag at MALL
            asm volatile("s_waitcnt vmcnt(0)" ::: "memory");
            if (lane == 0)
                (void)__hip_atomic_exchange(flags + fbase + (s + 1), 1,
                                            __ATOMIC_RELAXED, __HIP_MEMORY_SCOPE_AGENT);
        }
    }
}

}  // namespace

extern "C" void kernel_launch(void* const* d_in, const int* in_sizes, int n_in,
                              void* d_out, int out_size, void* d_ws, size_t ws_size,
                              hipStream_t stream) {
    const float* xs  = (const float*)d_in[0];
    const float* ks  = (const float*)d_in[1];
    const int*   pm  = (const int*)d_in[2];
    const float* dxv = (const float*)d_in[3];
    const float* dtv = (const float*)d_in[4];
    // d_in[5] = t_coords: only carries the (NT, NX) shape; values unused.
    float* out = (float*)d_out;

    int* flags = (int*)((char*)d_ws + kFlagsOff);
    int* halo  = (int*)((char*)d_ws + kHaloOff);

    // Flags must be zeroed every call (d_ws is not re-poisoned between replays).
    hipMemsetAsync(flags, 0, kFlagsBytes, stream);

    hipLaunchKernelGGL(godunov_fused, dim3(kB * 16), dim3(64), 0, stream,
                       xs, ks, pm, dxv, dtv, out, flags, halo);
}